// Round 4
// baseline (1235.027 us; speedup 1.0000x reference)
//
#include <hip/hip_runtime.h>
#include <hip/hip_bf16.h>
#include <cstddef>

// Problem constants
#define NB 64      // batch
#define LL 128     // L1 == L2
#define EE 300     // embed dim
#define DD 256     // hidden dim
#define NLAYERS 10
#define MROWS (NB * LL)  // 8192

static constexpr float BN_SC = 0.9995003746877562f;  // 1/sqrt(1+1e-3)

typedef unsigned short u16;
typedef __attribute__((ext_vector_type(4))) unsigned short us4;
typedef __attribute__((ext_vector_type(8))) unsigned short us8;
typedef __attribute__((ext_vector_type(8))) short bfrag;   // 8 bf16 (4 VGPR)
typedef __attribute__((ext_vector_type(4))) float f4;      // MFMA C/D

__device__ __forceinline__ u16 f2bf(float x) {
  union { float f; unsigned u; } v; v.f = x;
  unsigned r = v.u + 0x7FFFu + ((v.u >> 16) & 1u);  // RNE
  return (u16)(r >> 16);
}
__device__ __forceinline__ float bf2f(u16 s) {
  union { unsigned u; float f; } v; v.u = (unsigned)s << 16;
  return v.f;
}
__device__ __forceinline__ float4 ld4(const float* p) { return *(const float4*)p; }

// ---------------- async global->LDS staging (16B/lane) -------------------
__device__ __forceinline__ void async16(void* lds, const void* g) {
  __builtin_amdgcn_global_load_lds(
      (const __attribute__((address_space(1))) unsigned int*)g,
      (__attribute__((address_space(3))) unsigned int*)lds, 16, 0, 0);
}

// ===== 512-thread staging: [128 rows][32 k] (8KB), one async16/thread =====
__device__ __forceinline__ void stage128(const u16* __restrict__ src, int ld,
                                         int r0, int k0, u16* lds, int t) {
  const int w = t >> 6;
  const int c = t;  // chunk 0..511: row=c>>2, part=c&3
  async16((char*)lds + w * 1024,
          src + (size_t)(r0 + (c >> 2)) * ld + k0 + (c & 3) * 8);
}
// [256 rows][32 k] (16KB), two async16/thread
__device__ __forceinline__ void stage256(const u16* __restrict__ src, int ld,
                                         int r0, int k0, u16* lds, int t) {
  const int w = t >> 6;
  int c = t;
  async16((char*)lds + w * 1024,
          src + (size_t)(r0 + (c >> 2)) * ld + k0 + (c & 3) * 8);
  c = t + 512;
  async16((char*)lds + 8192 + w * 1024,
          src + (size_t)(r0 + (c >> 2)) * ld + k0 + (c & 3) * 8);
}

__device__ __forceinline__ bfrag fragld(const u16* T, int row, int fq) {
  return *(const bfrag*)&T[row * 32 + fq * 8];
}

// swizzled byte offset into a [128][128] bf16 LDS matrix (conflict-free b128 reads)
__device__ __forceinline__ int eswz(int row, int colbyte) {
  return (row * 256 + colbyte) ^ ((row & 7) << 4);
}
__device__ __forceinline__ bfrag ldsE(const u16* E, int row, int colbyte) {
  return *(const bfrag*)((const char*)E + eswz(row, colbyte));
}

// ---------------- weight transpose-convert: dst[n][k]=bf16(src[k][n]) ----
__global__ __launch_bounds__(256)
void txw(const float* __restrict__ src, u16* __restrict__ dst, int K, int N, int Kpad) {
  src += (size_t)blockIdx.z * K * N;
  dst += (size_t)blockIdx.z * N * Kpad;
  __shared__ float tileS[64][65];
  const int k0 = blockIdx.x * 64, n0 = blockIdx.y * 64;
  const int t = threadIdx.x;
  {
    const int kr = t >> 2, nc = (t & 3) * 16;
    const int k = k0 + kr;
#pragma unroll
    for (int j = 0; j < 16; j += 4) {
      float4 v = (k < K) ? ld4(src + (size_t)k * N + n0 + nc + j)
                         : make_float4(0.f, 0.f, 0.f, 0.f);
      tileS[kr][nc + j + 0] = v.x; tileS[kr][nc + j + 1] = v.y;
      tileS[kr][nc + j + 2] = v.z; tileS[kr][nc + j + 3] = v.w;
    }
  }
  __syncthreads();
  {
    const int nr = t >> 2, kc = (t & 3) * 16;
    us8 o0, o1;
#pragma unroll
    for (int j = 0; j < 8; ++j) {
      o0[j] = f2bf(tileS[kc + j][nr]);
      o1[j] = f2bf(tileS[kc + 8 + j][nr]);
    }
    u16* d = dst + (size_t)(n0 + nr) * Kpad + k0 + kc;
    *(us8*)d = o0;
    *(us8*)(d + 8) = o1;
  }
}

// ---------------- embed gather -> bf16, pad 300->320 ---------------------
__global__ __launch_bounds__(256)
void gather_embed(const float* __restrict__ emb, const int* __restrict__ ids1,
                  const int* __restrict__ ids2, u16* __restrict__ E1,
                  u16* __restrict__ E2) {
  const int side = blockIdx.y;
  const int* ids = side ? ids2 : ids1;
  u16* E = side ? E2 : E1;
  const int row = blockIdx.x * 4 + (threadIdx.x >> 6);
  const int lane = threadIdx.x & 63;
  const float* src = emb + (size_t)ids[row] * EE;
  u16* dst = E + (size_t)row * 320;
#pragma unroll
  for (int j = 0; j < 5; ++j) {
    const int c = lane + 64 * j;
    const float v = (c < EE) ? src[c] : 0.f;
    dst[c] = f2bf(v);
  }
}

// =================== whole layer, one block per batch =====================
__global__ __launch_bounds__(512, 2)
void layer_kernel(const u16* __restrict__ Xa, const u16* __restrict__ Xb,
                  int lda, int K1, int K1pad, const u16* __restrict__ W1t,
                  const float* __restrict__ b1v, const float* __restrict__ g1v,
                  const float* __restrict__ be1v,
                  const u16* __restrict__ Wt2L, const u16* __restrict__ WtgL,
                  const float* __restrict__ b2v, const float* __restrict__ g2v,
                  const float* __restrict__ be2v, const float* __restrict__ bgv,
                  u16* __restrict__ H1, u16* __restrict__ H2,
                  u16* __restrict__ HT1, u16* __restrict__ HT2,
                  u16* __restrict__ BETA, u16* __restrict__ ALPHA,
                  u16* __restrict__ X1o, u16* __restrict__ X2o) {
  const int b = blockIdx.x;
  __shared__ u16 Eh[128 * 128];     // 32KB row-normalized  (swizzled)
  __shared__ u16 Et[128 * 128];     // 32KB col-normalized^T (swizzled)
  __shared__ u16 stA[2][128 * 32];  // 16KB
  __shared__ u16 stB[2][256 * 32];  // 32KB
  __shared__ u16 stC[2][256 * 32];  // 32KB
  __shared__ float sqs[2][128];
  __shared__ float red[4][128];
  __shared__ float red2[2][128];

  const int t = threadIdx.x;
  const int lane = t & 63, w = t >> 6;
  const int wm = w >> 2, wn = w & 3;   // 2 x 4 wave grid
  const int fr = lane & 15, fq = lane >> 4;
  const int r0 = b * LL;

  // ---------- Phase 1: LBR both sides (H, H^T, sq-norms) ----------
  for (int s = 0; s < 2; ++s) {
    const u16* X = s ? Xb : Xa;
    u16* H = s ? H2 : H1;
    u16* HT = s ? HT2 : HT1;
    f4 acc[4][4] = {};
    const int nt = K1 / 32;
    stage128(X, lda, r0, 0, stA[0], t);
    stage256(W1t, K1pad, 0, 0, stB[0], t);
    __syncthreads();
    for (int ks = 0; ks < nt; ++ks) {
      const int cur = ks & 1;
      if (ks + 1 < nt) {
        stage128(X, lda, r0, (ks + 1) * 32, stA[cur ^ 1], t);
        stage256(W1t, K1pad, 0, (ks + 1) * 32, stB[cur ^ 1], t);
      }
      bfrag a[4], bb[4];
#pragma unroll
      for (int mi = 0; mi < 4; ++mi) a[mi] = fragld(stA[cur], wm * 64 + mi * 16 + fr, fq);
#pragma unroll
      for (int nj = 0; nj < 4; ++nj) bb[nj] = fragld(stB[cur], wn * 64 + nj * 16 + fr, fq);
#pragma unroll
      for (int mi = 0; mi < 4; ++mi)
#pragma unroll
        for (int nj = 0; nj < 4; ++nj)
          acc[mi][nj] = __builtin_amdgcn_mfma_f32_16x16x32_bf16(a[mi], bb[nj], acc[mi][nj], 0, 0, 0);
      __syncthreads();
    }
    float rsq[4][4] = {};
#pragma unroll
    for (int nj = 0; nj < 4; ++nj) {
      const int n = wn * 64 + nj * 16 + fr;
      const float sc = g1v[n] * BN_SC, bi = b1v[n], be = be1v[n];
#pragma unroll
      for (int mi = 0; mi < 4; ++mi) {
        const int m = wm * 64 + mi * 16 + fq * 4;
        us4 pk;
#pragma unroll
        for (int r = 0; r < 4; ++r) {
          const float x = sc * (acc[mi][nj][r] + bi) + be;
          const u16 hb = f2bf(fmaxf(x, 0.f));
          H[(size_t)(r0 + m + r) * DD + n] = hb;
          pk[r] = hb;
          const float h = bf2f(hb);
          rsq[mi][r] += h * h;
        }
        *(us4*)&HT[((size_t)b * DD + n) * LL + m] = pk;
      }
    }
#pragma unroll
    for (int mi = 0; mi < 4; ++mi)
#pragma unroll
      for (int r = 0; r < 4; ++r) {
        float v = rsq[mi][r];
        v += __shfl_xor(v, 1, 64); v += __shfl_xor(v, 2, 64);
        v += __shfl_xor(v, 4, 64); v += __shfl_xor(v, 8, 64);
        rsq[mi][r] = v;
      }
    if (fr == 0)
#pragma unroll
      for (int mi = 0; mi < 4; ++mi)
#pragma unroll
        for (int r = 0; r < 4; ++r)
          red[wn][wm * 64 + mi * 16 + fq * 4 + r] = rsq[mi][r];
    __syncthreads();
    if (t < 128) sqs[s][t] = red[0][t] + red[1][t] + red[2][t] + red[3][t];
    __syncthreads();
  }

  // ---------- Phase 2: att (E + in-block softmax norms -> LDS) ----------
  {
    f4 acc[4][2] = {};  // wave tile 64m x 32n
    stage128(H1, DD, r0, 0, stA[0], t);
    stage128(H2, DD, r0, 0, stB[0], t);
    __syncthreads();
    for (int ks = 0; ks < 8; ++ks) {
      const int cur = ks & 1;
      if (ks < 7) {
        stage128(H1, DD, r0, (ks + 1) * 32, stA[cur ^ 1], t);
        stage128(H2, DD, r0, (ks + 1) * 32, stB[cur ^ 1], t);
      }
      bfrag a[4], bb[2];
#pragma unroll
      for (int mi = 0; mi < 4; ++mi) a[mi] = fragld(stA[cur], wm * 64 + mi * 16 + fr, fq);
#pragma unroll
      for (int nj = 0; nj < 2; ++nj) bb[nj] = fragld(stB[cur], wn * 32 + nj * 16 + fr, fq);
#pragma unroll
      for (int mi = 0; mi < 4; ++mi)
#pragma unroll
        for (int nj = 0; nj < 2; ++nj)
          acc[mi][nj] = __builtin_amdgcn_mfma_f32_16x16x32_bf16(a[mi], bb[nj], acc[mi][nj], 0, 0, 0);
      __syncthreads();
    }
    float rp[4][4] = {};
    float cp[2] = {};
#pragma unroll
    for (int nj = 0; nj < 2; ++nj) {
      const int n = wn * 32 + nj * 16 + fr;
      const float s2 = sqs[1][n];
#pragma unroll
      for (int mi = 0; mi < 4; ++mi) {
        const int m = wm * 64 + mi * 16 + fq * 4;
#pragma unroll
        for (int r = 0; r < 4; ++r) {
          const float d = sqs[0][m + r] + s2 - 2.f * acc[mi][nj][r];
          const float e = __expf(1.f / (1.f + d));
          acc[mi][nj][r] = e;
          rp[mi][r] += e;
          cp[nj] += e;
        }
      }
    }
#pragma unroll
    for (int mi = 0; mi < 4; ++mi)
#pragma unroll
      for (int r = 0; r < 4; ++r) {
        float v = rp[mi][r];
        v += __shfl_xor(v, 1, 64); v += __shfl_xor(v, 2, 64);
        v += __shfl_xor(v, 4, 64); v += __shfl_xor(v, 8, 64);
        rp[mi][r] = v;
      }
#pragma unroll
    for (int nj = 0; nj < 2; ++nj) {
      float v = cp[nj];
      v += __shfl_xor(v, 16, 64); v += __shfl_xor(v, 32, 64);
      cp[nj] = v;
    }
    if (fr == 0)
#pragma unroll
      for (int mi = 0; mi < 4; ++mi)
#pragma unroll
        for (int r = 0; r < 4; ++r)
          red[wn][wm * 64 + mi * 16 + fq * 4 + r] = rp[mi][r];
    if (fq == 0)
#pragma unroll
      for (int nj = 0; nj < 2; ++nj)
        red2[wm][wn * 32 + nj * 16 + fr] = cp[nj];
    __syncthreads();
    float riv[4][4];
#pragma unroll
    for (int mi = 0; mi < 4; ++mi)
#pragma unroll
      for (int r = 0; r < 4; ++r) {
        const int m = wm * 64 + mi * 16 + fq * 4 + r;
        riv[mi][r] = 1.f / (red[0][m] + red[1][m] + red[2][m] + red[3][m]);
      }
#pragma unroll
    for (int nj = 0; nj < 2; ++nj) {
      const int n = wn * 32 + nj * 16 + fr;
      const float civ = 1.f / (red2[0][n] + red2[1][n]);
#pragma unroll
      for (int mi = 0; mi < 4; ++mi) {
        const int m = wm * 64 + mi * 16 + fq * 4;
        us4 pk;
#pragma unroll
        for (int r = 0; r < 4; ++r) {
          const float e = acc[mi][nj][r];
          *(u16*)((char*)Eh + eswz(m + r, n * 2)) = f2bf(e * riv[mi][r]);
          pk[r] = f2bf(e * civ);
        }
        *(us4*)((char*)Et + eswz(n, m * 2)) = pk;
      }
    }
    __syncthreads();
  }

  // ---------- Phase 3: BETA = Eh @ H2 ; ALPHA = Et @ H1 ----------
  for (int s = 0; s < 2; ++s) {
    const u16* Elds = s ? Et : Eh;
    const u16* HT = s ? HT1 : HT2;
    u16* O = s ? ALPHA : BETA;
    f4 acc[4][4] = {};
    stage256(HT, LL, b * DD, 0, stB[0], t);
    __syncthreads();
    for (int ks = 0; ks < 4; ++ks) {
      const int cur = ks & 1;
      if (ks < 3) stage256(HT, LL, b * DD, (ks + 1) * 32, stB[cur ^ 1], t);
      bfrag a[4], bb[4];
#pragma unroll
      for (int mi = 0; mi < 4; ++mi)
        a[mi] = ldsE(Elds, wm * 64 + mi * 16 + fr, ks * 64 + fq * 16);
#pragma unroll
      for (int nj = 0; nj < 4; ++nj) bb[nj] = fragld(stB[cur], wn * 64 + nj * 16 + fr, fq);
#pragma unroll
      for (int mi = 0; mi < 4; ++mi)
#pragma unroll
        for (int nj = 0; nj < 4; ++nj)
          acc[mi][nj] = __builtin_amdgcn_mfma_f32_16x16x32_bf16(a[mi], bb[nj], acc[mi][nj], 0, 0, 0);
      __syncthreads();
    }
#pragma unroll
    for (int nj = 0; nj < 4; ++nj) {
      const int n = wn * 64 + nj * 16 + fr;
#pragma unroll
      for (int mi = 0; mi < 4; ++mi) {
        const int m = wm * 64 + mi * 16 + fq * 4;
#pragma unroll
        for (int r = 0; r < 4; ++r)
          O[(size_t)(r0 + m + r) * DD + n] = f2bf(acc[mi][nj][r]);
      }
    }
  }

  // ---------- Phase 4: vg (fused W2 || Wg + gate update) ----------
  for (int s = 0; s < 2; ++s) {
    const u16* H = s ? H2 : H1;
    const u16* CC = s ? ALPHA : BETA;
    u16* Xo = s ? X2o : X1o;
    f4 av[4][4] = {}, ag[4][4] = {};
    __syncthreads();  // ensure prior phase/side done with staging bufs
    stage128(H, DD, r0, 0, stA[0], t);
    stage256(Wt2L, 2 * DD, 0, 0, stB[0], t);
    stage256(WtgL, DD, 0, 0, stC[0], t);
    __syncthreads();
    for (int ks = 0; ks < 16; ++ks) {
      const int cur = ks & 1;
      if (ks + 1 < 16) {
        const u16* Asrc = (ks + 1 < 8) ? H : CC;
        stage128(Asrc, DD, r0, ((ks + 1) & 7) * 32, stA[cur ^ 1], t);
        stage256(Wt2L, 2 * DD, 0, (ks + 1) * 32, stB[cur ^ 1], t);
        if (ks + 1 < 8) stage256(WtgL, DD, 0, (ks + 1) * 32, stC[cur ^ 1], t);
      }
      bfrag a[4], b2[4];
#pragma unroll
      for (int mi = 0; mi < 4; ++mi) a[mi] = fragld(stA[cur], wm * 64 + mi * 16 + fr, fq);
#pragma unroll
      for (int nj = 0; nj < 4; ++nj) b2[nj] = fragld(stB[cur], wn * 64 + nj * 16 + fr, fq);
      if (ks < 8) {
        bfrag bg[4];
#pragma unroll
        for (int nj = 0; nj < 4; ++nj) bg[nj] = fragld(stC[cur], wn * 64 + nj * 16 + fr, fq);
#pragma unroll
        for (int mi = 0; mi < 4; ++mi)
#pragma unroll
          for (int nj = 0; nj < 4; ++nj) {
            av[mi][nj] = __builtin_amdgcn_mfma_f32_16x16x32_bf16(a[mi], b2[nj], av[mi][nj], 0, 0, 0);
            ag[mi][nj] = __builtin_amdgcn_mfma_f32_16x16x32_bf16(a[mi], bg[nj], ag[mi][nj], 0, 0, 0);
          }
      } else {
#pragma unroll
        for (int mi = 0; mi < 4; ++mi)
#pragma unroll
          for (int nj = 0; nj < 4; ++nj)
            av[mi][nj] = __builtin_amdgcn_mfma_f32_16x16x32_bf16(a[mi], b2[nj], av[mi][nj], 0, 0, 0);
      }
      __syncthreads();
    }
#pragma unroll
    for (int nj = 0; nj < 4; ++nj) {
      const int n = wn * 64 + nj * 16 + fr;
      const float sc = g2v[n] * BN_SC, bi = b2v[n], be = be2v[n], bgn = bgv[n];
#pragma unroll
      for (int mi = 0; mi < 4; ++mi) {
        const int m = wm * 64 + mi * 16 + fq * 4;
#pragma unroll
        for (int r = 0; r < 4; ++r) {
          const float v = fmaxf(sc * (av[mi][nj][r] + bi) + be, 0.f);
          const float g = 1.f / (1.f + __expf(-(ag[mi][nj][r] + bgn)));
          const float h = bf2f(H[(size_t)(r0 + m + r) * DD + n]);
          Xo[(size_t)(r0 + m + r) * DD + n] = f2bf(v * g + h * (1.f - g));
        }
      }
    }
  }
}

// ============== 256-thread helpers for the MLP (4-wave) ===================
__device__ __forceinline__ void stage_tile(const u16* __restrict__ src, int ld,
                                           int r0, int k0, u16* lds, int t) {
  const int w = t >> 6;
  int c = w * 64 + (t & 63);
  async16((char*)lds + w * 1024,
          src + (size_t)(r0 + (c >> 2)) * ld + k0 + (c & 3) * 8);
  c += 256;
  async16((char*)lds + 4096 + w * 1024,
          src + (size_t)(r0 + (c >> 2)) * ld + k0 + (c & 3) * 8);
}
__device__ __forceinline__ void mfma_step4(const u16* As, const u16* Bs, int wm,
                                           int wn, int fr, int fq, f4 acc[4][4]) {
  bfrag a[4], b[4];
#pragma unroll
  for (int i = 0; i < 4; ++i) a[i] = *(const bfrag*)&As[(wm * 64 + i * 16 + fr) * 32 + fq * 8];
#pragma unroll
  for (int j = 0; j < 4; ++j) b[j] = *(const bfrag*)&Bs[(wn * 64 + j * 16 + fr) * 32 + fq * 8];
#pragma unroll
  for (int i = 0; i < 4; ++i)
#pragma unroll
    for (int j = 0; j < 4; ++j)
      acc[i][j] = __builtin_amdgcn_mfma_f32_16x16x32_bf16(a[i], b[j], acc[i][j], 0, 0, 0);
}

// MLP split-K GEMM: partial[ky] = (Ah+Al) @ Wt-slice  (fp32 partials)
__global__ __launch_bounds__(256)
void mlp_sk(const u16* __restrict__ Ah, const u16* __restrict__ Al,
            const u16* __restrict__ Wt, float* __restrict__ PART) {
  const int n0 = blockIdx.x * 128;
  const int kb = blockIdx.y * 8;  // 8 K-steps of 32 per slice
  __shared__ u16 sAh[2][4096], sAl[2][4096], sW[2][4096];
  const int t = threadIdx.x;
  const int lane = t & 63, w = t >> 6, wm = w >> 1, wn = w & 1;
  const int fr = lane & 15, fq = lane >> 4;
  f4 acc[4][4] = {};
  stage_tile(Ah, 1024, 0, kb * 32, sAh[0], t);
  stage_tile(Al, 1024, 0, kb * 32, sAl[0], t);
  stage_tile(Wt, 1024, n0, kb * 32, sW[0], t);
  __syncthreads();
  for (int ks = 0; ks < 8; ++ks) {
    const int cur = ks & 1;
    if (ks < 7) {
      stage_tile(Ah, 1024, 0, (kb + ks + 1) * 32, sAh[cur ^ 1], t);
      stage_tile(Al, 1024, 0, (kb + ks + 1) * 32, sAl[cur ^ 1], t);
      stage_tile(Wt, 1024, n0, (kb + ks + 1) * 32, sW[cur ^ 1], t);
    }
    mfma_step4(sAh[cur], sW[cur], wm, wn, fr, fq, acc);
    mfma_step4(sAl[cur], sW[cur], wm, wn, fr, fq, acc);
    __syncthreads();
  }
#pragma unroll
  for (int nj = 0; nj < 4; ++nj) {
    const int n = n0 + wn * 64 + nj * 16 + fr;
#pragma unroll
    for (int mi = 0; mi < 4; ++mi) {
      const int m = wm * 64 + mi * 16 + fq * 4;
#pragma unroll
      for (int r = 0; r < 4; ++r)
        PART[((size_t)blockIdx.y * 128 + m + r) * 1024 + n] = acc[mi][nj][r];
    }
  }
}

// combine 4 partials + bias + relu -> hi/lo bf16 (or fp32)
__global__ __launch_bounds__(512)
void mlp_comb(const float* __restrict__ P, const float* __restrict__ bias,
              u16* __restrict__ Oh, u16* __restrict__ Ol,
              float* __restrict__ Of) {
#pragma unroll
  for (int e = 0; e < 8; ++e) {
    const int idx = blockIdx.x * 4096 + e * 512 + threadIdx.x;
    const int col = idx & 1023;
    float s = P[idx] + P[131072 + idx] + P[262144 + idx] + P[393216 + idx] + bias[col];
    s = fmaxf(s, 0.f);
    if (Oh) {
      const u16 h = f2bf(s);
      Oh[idx] = h;
      Ol[idx] = f2bf(s - bf2f(h));
    } else {
      Of[idx] = s;
    }
  }
}

// ---------------- pool -> bf16 hi/lo [128 rows][1024], pad rows zeroed ---
__global__ __launch_bounds__(256)
void pool_kernel(const u16* __restrict__ X1, const u16* __restrict__ X2,
                 u16* __restrict__ VPh, u16* __restrict__ VPl) {
  const int b = blockIdx.x;
  const int d = threadIdx.x;  // 256
  const u16* x1 = X1 + (size_t)b * LL * DD;
  const u16* x2 = X2 + (size_t)b * LL * DD;
  float mx1 = -1e30f, s1 = 0.f, mx2 = -1e30f, s2 = 0.f;
  for (int i = 0; i < LL; ++i) {
    const float v1 = bf2f(x1[(size_t)i * DD + d]);
    mx1 = fmaxf(mx1, v1); s1 += v1;
    const float v2 = bf2f(x2[(size_t)i * DD + d]);
    mx2 = fmaxf(mx2, v2); s2 += v2;
  }
  const float vals[4] = {mx1, mx2, s1, s2};
#pragma unroll
  for (int q = 0; q < 4; ++q) {
    const float v = vals[q];
    const u16 h = f2bf(v);
    VPh[(size_t)b * 1024 + q * 256 + d] = h;
    VPl[(size_t)b * 1024 + q * 256 + d] = f2bf(v - bf2f(h));
  }
  for (int j = d; j < 1024; j += 256) {
    VPh[(size_t)(64 + b) * 1024 + j] = 0;
    VPl[(size_t)(64 + b) * 1024 + j] = 0;
  }
}

__global__ __launch_bounds__(256)
void out_kernel(const float* __restrict__ T2, const float* __restrict__ Wout,
                const float* __restrict__ bout, float* __restrict__ out) {
  const int b = blockIdx.x;
  const int t = threadIdx.x;  // 256
  float a0 = 0.f, a1 = 0.f, a2 = 0.f;
  for (int k = t; k < 1024; k += 256) {
    const float x = T2[(size_t)b * 1024 + k];
    a0 = fmaf(x, Wout[k * 3 + 0], a0);
    a1 = fmaf(x, Wout[k * 3 + 1], a1);
    a2 = fmaf(x, Wout[k * 3 + 2], a2);
  }
  __shared__ float red[3][256];
  red[0][t] = a0; red[1][t] = a1; red[2][t] = a2;
  __syncthreads();
  for (int off = 128; off > 0; off >>= 1) {
    if (t < off) {
      red[0][t] += red[0][t + off];
      red[1][t] += red[1][t + off];
      red[2][t] += red[2][t + off];
    }
    __syncthreads();
  }
  if (t < 3) out[b * 3 + t] = red[t][0] + bout[t];
}

extern "C" void kernel_launch(void* const* d_in, const int* in_sizes, int n_in,
                              void* d_out, int out_size, void* d_ws, size_t ws_size,
                              hipStream_t stream) {
  (void)in_sizes; (void)n_in; (void)out_size; (void)ws_size;
  const float* embed = (const float*)d_in[0];
  const float* W1f   = (const float*)d_in[1];
  const float* W1r   = (const float*)d_in[2];
  const float* b1    = (const float*)d_in[3];
  const float* bn1g  = (const float*)d_in[4];
  const float* bn1b  = (const float*)d_in[5];
  const float* W2    = (const float*)d_in[6];
  const float* b2    = (const float*)d_in[7];
  const float* bn2g  = (const float*)d_in[8];
  const float* bn2b  = (const float*)d_in[9];
  const float* Wg    = (const float*)d_in[10];
  const float* bg    = (const float*)d_in[11];
  const float* Wf1   = (const float*)d_in[12];
  const float* bf1   = (const float*)d_in[13];
  const float* Wf2   = (const float*)d_in[14];
  const float* bf2   = (const float*)d_in[15];
  const float* Wout  = (const float*)d_in[16];
  const float* bout  = (const float*)d_in[17];
  const int* ids1    = (const int*)d_in[18];
  const int* ids2    = (const int*)d_in[19];

  char* wsp = (char*)d_ws;
  auto alloc = [&](size_t bytes) {
    char* p = wsp;
    wsp += (bytes + 255) & ~(size_t)255;
    return p;
  };
  u16* Hbf1  = (u16*)alloc((size_t)MROWS * DD * 2);
  u16* Hbf2  = (u16*)alloc((size_t)MROWS * DD * 2);
  u16* HT1   = (u16*)alloc((size_t)MROWS * DD * 2);
  u16* HT2   = (u16*)alloc((size_t)MROWS * DD * 2);
  u16* Xbf1  = (u16*)alloc((size_t)MROWS * 320 * 2);
  u16* Xbf2  = (u16*)alloc((size_t)MROWS * 320 * 2);
  u16* BETAb = (u16*)alloc((size_t)MROWS * DD * 2);
  u16* ALPHAb= (u16*)alloc((size_t)MROWS * DD * 2);
  u16* Wt1f  = (u16*)alloc((size_t)DD * 320 * 2);
  u16* Wt1r  = (u16*)alloc((size_t)9 * DD * DD * 2);
  u16* Wt2   = (u16*)alloc((size_t)10 * DD * 2 * DD * 2);
  u16* Wtg   = (u16*)alloc((size_t)10 * DD * DD * 2);
  u16* Wf1t  = (u16*)alloc((size_t)1024 * 1024 * 2);
  u16* Wf2t  = (u16*)alloc((size_t)1024 * 1024 * 2);
  u16* VPh   = (u16*)alloc((size_t)128 * 1024 * 2);
  u16* VPl   = (u16*)alloc((size_t)128 * 1024 * 2);
  u16* T1h   = (u16*)alloc((size_t)128 * 1024 * 2);
  u16* T1l   = (u16*)alloc((size_t)128 * 1024 * 2);
  float* T2f = (float*)alloc((size_t)128 * 1024 * 4);
  float* PART1 = (float*)alloc((size_t)4 * 128 * 1024 * 4);
  float* PART2 = (float*)alloc((size_t)4 * 128 * 1024 * 4);

  // weight conversion (transpose to n-major bf16)
  txw<<<dim3(5, 4, 1), 256, 0, stream>>>(W1f, Wt1f, EE, DD, 320);
  txw<<<dim3(4, 4, 9), 256, 0, stream>>>(W1r, Wt1r, DD, DD, DD);
  txw<<<dim3(8, 4, 10), 256, 0, stream>>>(W2, Wt2, 2 * DD, DD, 2 * DD);
  txw<<<dim3(4, 4, 10), 256, 0, stream>>>(Wg, Wtg, DD, DD, DD);
  txw<<<dim3(16, 16, 1), 256, 0, stream>>>(Wf1, Wf1t, 1024, 1024, 1024);
  txw<<<dim3(16, 16, 1), 256, 0, stream>>>(Wf2, Wf2t, 1024, 1024, 1024);
  gather_embed<<<dim3(MROWS / 4, 2), 256, 0, stream>>>(embed, ids1, ids2, Xbf1, Xbf2);

  for (int i = 0; i < NLAYERS; ++i) {
    const u16* Wt1 = (i == 0) ? Wt1f : (Wt1r + (size_t)(i - 1) * DD * DD);
    const int K1 = (i == 0) ? 320 : DD;
    const int lda = (i == 0) ? 320 : DD;
    layer_kernel<<<NB, 512, 0, stream>>>(
        Xbf1, Xbf2, lda, K1, K1, Wt1,
        b1 + i * DD, bn1g + i * DD, bn1b + i * DD,
        Wt2 + (size_t)i * DD * 2 * DD, Wtg + (size_t)i * DD * DD,
        b2 + i * DD, bn2g + i * DD, bn2b + i * DD, bg + i * DD,
        Hbf1, Hbf2, HT1, HT2, BETAb, ALPHAb, Xbf1, Xbf2);
  }
  pool_kernel<<<NB, DD, 0, stream>>>(Xbf1, Xbf2, VPh, VPl);
  mlp_sk<<<dim3(8, 4), 256, 0, stream>>>(VPh, VPl, Wf1t, PART1);
  mlp_comb<<<32, 512, 0, stream>>>(PART1, bf1, T1h, T1l, nullptr);
  mlp_sk<<<dim3(8, 4), 256, 0, stream>>>(T1h, T1l, Wf2t, PART2);
  mlp_comb<<<32, 512, 0, stream>>>(PART2, bf2, nullptr, nullptr, T2f);
  out_kernel<<<NB, 256, 0, stream>>>(T2f, Wout, bout, (float*)d_out);
}

// Round 5
// 742.715 us; speedup vs baseline: 1.6629x; 1.6629x over previous
//
#include <hip/hip_runtime.h>
#include <hip/hip_bf16.h>
#include <cstddef>

// Problem constants
#define NB 64      // batch
#define LL 128     // L1 == L2
#define EE 300     // embed dim
#define DD 256     // hidden dim
#define NLAYERS 10
#define MROWS (NB * LL)  // 8192

static constexpr float BN_SC = 0.9995003746877562f;  // 1/sqrt(1+1e-3)

typedef unsigned short u16;
typedef __attribute__((ext_vector_type(4))) unsigned short us4;
typedef __attribute__((ext_vector_type(8))) unsigned short us8;
typedef __attribute__((ext_vector_type(8))) short bfrag;   // 8 bf16 (4 VGPR)
typedef __attribute__((ext_vector_type(4))) float f4;      // MFMA C/D

#define MFMA_B16(a, b, c) __builtin_amdgcn_mfma_f32_16x16x32_bf16(a, b, c, 0, 0, 0)

__device__ __forceinline__ u16 f2bf(float x) {
  union { float f; unsigned u; } v; v.f = x;
  unsigned r = v.u + 0x7FFFu + ((v.u >> 16) & 1u);  // RNE
  return (u16)(r >> 16);
}
__device__ __forceinline__ float bf2f(u16 s) {
  union { unsigned u; float f; } v; v.u = (unsigned)s << 16;
  return v.f;
}
__device__ __forceinline__ float4 ld4(const float* p) { return *(const float4*)p; }

// direct MFMA fragment load from row-major [row][k] bf16 global (L2-hot)
__device__ __forceinline__ bfrag gfrag(const u16* __restrict__ p, int ld, int row, int k) {
  return *(const bfrag*)(p + (size_t)row * ld + k);
}

// swizzled byte offset into a [128][128] bf16 LDS matrix (conflict-free b128 reads)
__device__ __forceinline__ int eswz(int row, int colbyte) {
  return (row * 256 + colbyte) ^ ((row & 7) << 4);
}
__device__ __forceinline__ bfrag ldsE(const u16* E, int row, int colbyte) {
  return *(const bfrag*)((const char*)E + eswz(row, colbyte));
}

// ---------------- weight transpose-convert: dst[n][k]=bf16(src[k][n]) ----
__global__ __launch_bounds__(256)
void txw(const float* __restrict__ src, u16* __restrict__ dst, int K, int N, int Kpad) {
  src += (size_t)blockIdx.z * K * N;
  dst += (size_t)blockIdx.z * N * Kpad;
  __shared__ float tileS[64][65];
  const int k0 = blockIdx.x * 64, n0 = blockIdx.y * 64;
  const int t = threadIdx.x;
  {
    const int kr = t >> 2, nc = (t & 3) * 16;
    const int k = k0 + kr;
#pragma unroll
    for (int j = 0; j < 16; j += 4) {
      float4 v = (k < K) ? ld4(src + (size_t)k * N + n0 + nc + j)
                         : make_float4(0.f, 0.f, 0.f, 0.f);
      tileS[kr][nc + j + 0] = v.x; tileS[kr][nc + j + 1] = v.y;
      tileS[kr][nc + j + 2] = v.z; tileS[kr][nc + j + 3] = v.w;
    }
  }
  __syncthreads();
  {
    const int nr = t >> 2, kc = (t & 3) * 16;
    us8 o0, o1;
#pragma unroll
    for (int j = 0; j < 8; ++j) {
      o0[j] = f2bf(tileS[kc + j][nr]);
      o1[j] = f2bf(tileS[kc + 8 + j][nr]);
    }
    u16* d = dst + (size_t)(n0 + nr) * Kpad + k0 + kc;
    *(us8*)d = o0;
    *(us8*)(d + 8) = o1;
  }
}

// ---------------- embed gather -> bf16, pad 300->320 ---------------------
__global__ __launch_bounds__(256)
void gather_embed(const float* __restrict__ emb, const int* __restrict__ ids1,
                  const int* __restrict__ ids2, u16* __restrict__ E1,
                  u16* __restrict__ E2) {
  const int side = blockIdx.y;
  const int* ids = side ? ids2 : ids1;
  u16* E = side ? E2 : E1;
  const int row = blockIdx.x * 4 + (threadIdx.x >> 6);
  const int lane = threadIdx.x & 63;
  const float* src = emb + (size_t)ids[row] * EE;
  u16* dst = E + (size_t)row * 320;
#pragma unroll
  for (int j = 0; j < 5; ++j) {
    const int c = lane + 64 * j;
    const float v = (c < EE) ? src[c] : 0.f;
    dst[c] = f2bf(v);
  }
}

// ---------------- LBR-1 no-LDS: H = relu(bn(A@W1+b)), + H^T + sqnorms ----
template <int NT>
__device__ __forceinline__ void lbr_core(const u16* __restrict__ A, int lda, int am0,
                                         const u16* __restrict__ B, int ldb, int bn0,
                                         int fr, int fq, f4 acc[4][2]) {
#pragma unroll
  for (int ks = 0; ks < NT; ++ks) {
    bfrag a[4], b[2];
#pragma unroll
    for (int mi = 0; mi < 4; ++mi)
      a[mi] = gfrag(A, lda, am0 + mi * 16 + fr, ks * 32 + fq * 8);
#pragma unroll
    for (int nj = 0; nj < 2; ++nj)
      b[nj] = gfrag(B, ldb, bn0 + nj * 16 + fr, ks * 32 + fq * 8);
#pragma unroll
    for (int mi = 0; mi < 4; ++mi)
#pragma unroll
      for (int nj = 0; nj < 2; ++nj) acc[mi][nj] = MFMA_B16(a[mi], b[nj], acc[mi][nj]);
  }
}

__global__ __launch_bounds__(256, 2)
void lbr_nl(const u16* __restrict__ Xa, const u16* __restrict__ Xb, int lda, int K1,
            const u16* __restrict__ W1t,
            const float* __restrict__ b1v, const float* __restrict__ g1v,
            const float* __restrict__ be1v,
            u16* __restrict__ H1, u16* __restrict__ H2,
            u16* __restrict__ HT1, u16* __restrict__ HT2,
            float* __restrict__ SQP1, float* __restrict__ SQP2) {
  const int side = blockIdx.z;
  const u16* A = side ? Xb : Xa;
  u16* H = side ? H2 : H1;
  u16* HT = side ? HT2 : HT1;
  float* SQP = side ? SQP2 : SQP1;
  const int t = threadIdx.x, lane = t & 63, w = t >> 6;
  const int wm = w >> 1, wn = w & 1;
  const int fr = lane & 15, fq = lane >> 4;
  const int m0 = blockIdx.x * 128, n0 = blockIdx.y * 64;
  f4 acc[4][2] = {};
  if (K1 == 256) lbr_core<8>(A, lda, m0 + wm * 64, W1t, K1, n0 + wn * 32, fr, fq, acc);
  else           lbr_core<10>(A, lda, m0 + wm * 64, W1t, K1, n0 + wn * 32, fr, fq, acc);
  const int bb = m0 >> 7;
  float rsq[4][4] = {};
#pragma unroll
  for (int nj = 0; nj < 2; ++nj) {
    const int n = n0 + wn * 32 + nj * 16 + fr;
    const float sc = g1v[n] * BN_SC, bi = b1v[n], be = be1v[n];
#pragma unroll
    for (int mi = 0; mi < 4; ++mi) {
      const int m = m0 + wm * 64 + mi * 16 + fq * 4;
      us4 pk;
#pragma unroll
      for (int r = 0; r < 4; ++r) {
        const float x = sc * (acc[mi][nj][r] + bi) + be;
        const u16 hb = f2bf(fmaxf(x, 0.f));
        H[(size_t)(m + r) * DD + n] = hb;
        pk[r] = hb;
        const float h = bf2f(hb);  // norms must match stored bf16 H
        rsq[mi][r] += h * h;
      }
      *(us4*)&HT[((size_t)bb * DD + n) * LL + (m & 127)] = pk;
    }
  }
#pragma unroll
  for (int mi = 0; mi < 4; ++mi)
#pragma unroll
    for (int r = 0; r < 4; ++r) {
      float v = rsq[mi][r];
      v += __shfl_xor(v, 1, 64); v += __shfl_xor(v, 2, 64);
      v += __shfl_xor(v, 4, 64); v += __shfl_xor(v, 8, 64);
      rsq[mi][r] = v;
    }
  if (fr == 0) {
    const int p = blockIdx.y * 2 + wn;  // 8 partials per row
#pragma unroll
    for (int mi = 0; mi < 4; ++mi)
#pragma unroll
      for (int r = 0; r < 4; ++r)
        SQP[(size_t)p * MROWS + m0 + wm * 64 + mi * 16 + fq * 4 + r] = rsq[mi][r];
  }
}

// ------- fused att+attn per (batch, N-half, side): E in LDS, PV out ------
__global__ __launch_bounds__(256, 2)
void attf(const u16* __restrict__ H1, const u16* __restrict__ H2,
          const float* __restrict__ SQP1, const float* __restrict__ SQP2,
          const u16* __restrict__ HT1, const u16* __restrict__ HT2,
          u16* __restrict__ BETA, u16* __restrict__ ALPHA) {
  const int b = blockIdx.x, nh = blockIdx.y, side = blockIdx.z;
  __shared__ u16 Elds[128 * 128];  // 32KB swizzled (Ê or Ê^T per side)
  __shared__ float sqs[2][128], rowp[2][128], colp[2][128];
  const int t = threadIdx.x, lane = t & 63, w = t >> 6;
  const int wm = w >> 1, wn = w & 1;
  const int fr = lane & 15, fq = lane >> 4;
  const int r0 = b * LL;
  if (t < 128) {
    float s = 0.f;
#pragma unroll
    for (int p = 0; p < 8; ++p) s += SQP1[(size_t)p * MROWS + r0 + t];
    sqs[0][t] = s;
  } else {
    const int u = t - 128;
    float s = 0.f;
#pragma unroll
    for (int p = 0; p < 8; ++p) s += SQP2[(size_t)p * MROWS + r0 + u];
    sqs[1][u] = s;
  }
  // QK^T: full 128x128 E, no-LDS frag loads
  f4 acc[4][4] = {};
#pragma unroll
  for (int ks = 0; ks < 8; ++ks) {
    bfrag a[4], bv[4];
#pragma unroll
    for (int mi = 0; mi < 4; ++mi)
      a[mi] = gfrag(H1, DD, r0 + wm * 64 + mi * 16 + fr, ks * 32 + fq * 8);
#pragma unroll
    for (int nj = 0; nj < 4; ++nj)
      bv[nj] = gfrag(H2, DD, r0 + wn * 64 + nj * 16 + fr, ks * 32 + fq * 8);
#pragma unroll
    for (int mi = 0; mi < 4; ++mi)
#pragma unroll
      for (int nj = 0; nj < 4; ++nj) acc[mi][nj] = MFMA_B16(a[mi], bv[nj], acc[mi][nj]);
  }
  __syncthreads();  // sqs visible
  float rp[4][4] = {}, cp[4] = {};
#pragma unroll
  for (int nj = 0; nj < 4; ++nj) {
    const int n = wn * 64 + nj * 16 + fr;
    const float s2 = sqs[1][n];
#pragma unroll
    for (int mi = 0; mi < 4; ++mi) {
      const int m = wm * 64 + mi * 16 + fq * 4;
#pragma unroll
      for (int r = 0; r < 4; ++r) {
        const float d = sqs[0][m + r] + s2 - 2.f * acc[mi][nj][r];
        const float e = __expf(1.f / (1.f + d));
        acc[mi][nj][r] = e;
        rp[mi][r] += e;
        cp[nj] += e;
      }
    }
  }
#pragma unroll
  for (int mi = 0; mi < 4; ++mi)
#pragma unroll
    for (int r = 0; r < 4; ++r) {
      float v = rp[mi][r];
      v += __shfl_xor(v, 1, 64); v += __shfl_xor(v, 2, 64);
      v += __shfl_xor(v, 4, 64); v += __shfl_xor(v, 8, 64);
      rp[mi][r] = v;
    }
#pragma unroll
  for (int nj = 0; nj < 4; ++nj) {
    float v = cp[nj];
    v += __shfl_xor(v, 16, 64); v += __shfl_xor(v, 32, 64);
    cp[nj] = v;
  }
  if (fr == 0)
#pragma unroll
    for (int mi = 0; mi < 4; ++mi)
#pragma unroll
      for (int r = 0; r < 4; ++r)
        rowp[wn][wm * 64 + mi * 16 + fq * 4 + r] = rp[mi][r];
  if (fq == 0)
#pragma unroll
    for (int nj = 0; nj < 4; ++nj)
      colp[wm][wn * 64 + nj * 16 + fr] = cp[nj];
  __syncthreads();
  if (side == 0) {  // row-normalized Ê
#pragma unroll
    for (int nj = 0; nj < 4; ++nj) {
      const int n = wn * 64 + nj * 16 + fr;
#pragma unroll
      for (int mi = 0; mi < 4; ++mi) {
        const int m = wm * 64 + mi * 16 + fq * 4;
#pragma unroll
        for (int r = 0; r < 4; ++r) {
          const float riv = 1.f / (rowp[0][m + r] + rowp[1][m + r]);
          *(u16*)((char*)Elds + eswz(m + r, n * 2)) = f2bf(acc[mi][nj][r] * riv);
        }
      }
    }
  } else {  // col-normalized Ê^T
#pragma unroll
    for (int nj = 0; nj < 4; ++nj) {
      const int n = wn * 64 + nj * 16 + fr;
      const float civ = 1.f / (colp[0][n] + colp[1][n]);
#pragma unroll
      for (int mi = 0; mi < 4; ++mi) {
        const int m = wm * 64 + mi * 16 + fq * 4;
        us4 pk;
#pragma unroll
        for (int r = 0; r < 4; ++r) pk[r] = f2bf(acc[mi][nj][r] * civ);
        *(us4*)((char*)Elds + eswz(n, m * 2)) = pk;
      }
    }
  }
  __syncthreads();
  // PV: O[m][d] = Ê @ H (B-frags from HT rows = H columns), N-half = 128
  const u16* HT = side ? HT1 : HT2;
  f4 pv[4][4] = {};
#pragma unroll
  for (int ks = 0; ks < 4; ++ks) {
    bfrag a[4], bv[4];
#pragma unroll
    for (int mi = 0; mi < 4; ++mi)
      a[mi] = ldsE(Elds, wm * 64 + mi * 16 + fr, ks * 64 + fq * 16);
#pragma unroll
    for (int nj = 0; nj < 4; ++nj)
      bv[nj] = gfrag(HT, LL, b * DD + nh * 128 + wn * 64 + nj * 16 + fr, ks * 32 + fq * 8);
#pragma unroll
    for (int mi = 0; mi < 4; ++mi)
#pragma unroll
      for (int nj = 0; nj < 4; ++nj) pv[mi][nj] = MFMA_B16(a[mi], bv[nj], pv[mi][nj]);
  }
  u16* O = side ? ALPHA : BETA;
#pragma unroll
  for (int nj = 0; nj < 4; ++nj) {
    const int n = nh * 128 + wn * 64 + nj * 16 + fr;
#pragma unroll
    for (int mi = 0; mi < 4; ++mi) {
      const int m = wm * 64 + mi * 16 + fq * 4;
#pragma unroll
      for (int r = 0; r < 4; ++r)
        O[(size_t)(r0 + m + r) * DD + n] = f2bf(pv[mi][nj][r]);
    }
  }
}

// ---------------- vg no-LDS: fused W2 || Wg + gate update ----------------
__global__ __launch_bounds__(256, 2)
void vg_nl(const u16* __restrict__ Hbf1, const u16* __restrict__ Hbf2,
           const u16* __restrict__ BETA, const u16* __restrict__ ALPHA,
           const u16* __restrict__ Wt2L, const u16* __restrict__ WtgL,
           const float* __restrict__ b2v, const float* __restrict__ g2v,
           const float* __restrict__ be2v, const float* __restrict__ bgv,
           u16* __restrict__ X1o, u16* __restrict__ X2o) {
  const int side = blockIdx.z;
  const u16* H = side ? Hbf2 : Hbf1;
  const u16* CC = side ? ALPHA : BETA;
  u16* Xo = side ? X2o : X1o;
  const int t = threadIdx.x, lane = t & 63, w = t >> 6;
  const int wm = w >> 1, wn = w & 1;
  const int fr = lane & 15, fq = lane >> 4;
  const int m0 = blockIdx.x * 128, n0 = blockIdx.y * 64;
  f4 accv[4][2] = {}, accg[4][2] = {};
#pragma unroll
  for (int ks = 0; ks < 8; ++ks) {  // A=H: W2 first half + Wg
    bfrag a[4], b2f[2], bgf[2];
#pragma unroll
    for (int mi = 0; mi < 4; ++mi)
      a[mi] = gfrag(H, DD, m0 + wm * 64 + mi * 16 + fr, ks * 32 + fq * 8);
#pragma unroll
    for (int nj = 0; nj < 2; ++nj) {
      b2f[nj] = gfrag(Wt2L, 2 * DD, n0 + wn * 32 + nj * 16 + fr, ks * 32 + fq * 8);
      bgf[nj] = gfrag(WtgL, DD, n0 + wn * 32 + nj * 16 + fr, ks * 32 + fq * 8);
    }
#pragma unroll
    for (int mi = 0; mi < 4; ++mi)
#pragma unroll
      for (int nj = 0; nj < 2; ++nj) {
        accv[mi][nj] = MFMA_B16(a[mi], b2f[nj], accv[mi][nj]);
        accg[mi][nj] = MFMA_B16(a[mi], bgf[nj], accg[mi][nj]);
      }
  }
#pragma unroll
  for (int ks = 0; ks < 8; ++ks) {  // A=CC: W2 second half
    bfrag a[4], b2f[2];
#pragma unroll
    for (int mi = 0; mi < 4; ++mi)
      a[mi] = gfrag(CC, DD, m0 + wm * 64 + mi * 16 + fr, ks * 32 + fq * 8);
#pragma unroll
    for (int nj = 0; nj < 2; ++nj)
      b2f[nj] = gfrag(Wt2L, 2 * DD, n0 + wn * 32 + nj * 16 + fr, DD + ks * 32 + fq * 8);
#pragma unroll
    for (int mi = 0; mi < 4; ++mi)
#pragma unroll
      for (int nj = 0; nj < 2; ++nj) accv[mi][nj] = MFMA_B16(a[mi], b2f[nj], accv[mi][nj]);
  }
#pragma unroll
  for (int nj = 0; nj < 2; ++nj) {
    const int n = n0 + wn * 32 + nj * 16 + fr;
    const float sc = g2v[n] * BN_SC, bi = b2v[n], be = be2v[n], bgn = bgv[n];
#pragma unroll
    for (int mi = 0; mi < 4; ++mi) {
      const int m = m0 + wm * 64 + mi * 16 + fq * 4;
#pragma unroll
      for (int r = 0; r < 4; ++r) {
        const float v = fmaxf(sc * (accv[mi][nj][r] + bi) + be, 0.f);
        const float g = 1.f / (1.f + __expf(-(accg[mi][nj][r] + bgn)));
        const float h = bf2f(H[(size_t)(m + r) * DD + n]);
        Xo[(size_t)(m + r) * DD + n] = f2bf(v * g + h * (1.f - g));
      }
    }
  }
}

// ---------------- pool -> bf16 hi/lo [128 rows][1024], pad rows zeroed ---
__global__ __launch_bounds__(256)
void pool_kernel(const u16* __restrict__ X1, const u16* __restrict__ X2,
                 u16* __restrict__ VPh, u16* __restrict__ VPl) {
  const int b = blockIdx.x;
  const int d = threadIdx.x;  // 256
  const u16* x1 = X1 + (size_t)b * LL * DD;
  const u16* x2 = X2 + (size_t)b * LL * DD;
  float mx1 = -1e30f, s1 = 0.f, mx2 = -1e30f, s2 = 0.f;
  for (int i = 0; i < LL; ++i) {
    const float v1 = bf2f(x1[(size_t)i * DD + d]);
    mx1 = fmaxf(mx1, v1); s1 += v1;
    const float v2 = bf2f(x2[(size_t)i * DD + d]);
    mx2 = fmaxf(mx2, v2); s2 += v2;
  }
  const float vals[4] = {mx1, mx2, s1, s2};
#pragma unroll
  for (int q = 0; q < 4; ++q) {
    const float v = vals[q];
    const u16 h = f2bf(v);
    VPh[(size_t)b * 1024 + q * 256 + d] = h;
    VPl[(size_t)b * 1024 + q * 256 + d] = f2bf(v - bf2f(h));
  }
  for (int j = d; j < 1024; j += 256) {
    VPh[(size_t)(64 + b) * 1024 + j] = 0;
    VPl[(size_t)(64 + b) * 1024 + j] = 0;
  }
}

// ---------------- MLP split-K no-LDS: PART[slice] = (Ah+Al) @ Wt-slice ---
__global__ __launch_bounds__(256, 2)
void mlp_sk(const u16* __restrict__ Ah, const u16* __restrict__ Al,
            const u16* __restrict__ Wt, float* __restrict__ PART) {
  const int n0 = blockIdx.x * 128;   // 8 N-blocks
  const int k0 = blockIdx.y * 128;   // 8 K-slices
  const int t = threadIdx.x, lane = t & 63, w = t >> 6;
  const int wm = w >> 1, wn = w & 1;
  const int fr = lane & 15, fq = lane >> 4;
  f4 acc[4][4] = {};
#pragma unroll
  for (int ks = 0; ks < 4; ++ks) {
    bfrag ah[4], al[4], bv[4];
#pragma unroll
    for (int mi = 0; mi < 4; ++mi) {
      ah[mi] = gfrag(Ah, 1024, wm * 64 + mi * 16 + fr, k0 + ks * 32 + fq * 8);
      al[mi] = gfrag(Al, 1024, wm * 64 + mi * 16 + fr, k0 + ks * 32 + fq * 8);
    }
#pragma unroll
    for (int nj = 0; nj < 4; ++nj)
      bv[nj] = gfrag(Wt, 1024, n0 + wn * 64 + nj * 16 + fr, k0 + ks * 32 + fq * 8);
#pragma unroll
    for (int mi = 0; mi < 4; ++mi)
#pragma unroll
      for (int nj = 0; nj < 4; ++nj) {
        acc[mi][nj] = MFMA_B16(ah[mi], bv[nj], acc[mi][nj]);
        acc[mi][nj] = MFMA_B16(al[mi], bv[nj], acc[mi][nj]);
      }
  }
#pragma unroll
  for (int nj = 0; nj < 4; ++nj) {
    const int n = n0 + wn * 64 + nj * 16 + fr;
#pragma unroll
    for (int mi = 0; mi < 4; ++mi) {
      const int m = wm * 64 + mi * 16 + fq * 4;
#pragma unroll
      for (int r = 0; r < 4; ++r)
        PART[((size_t)blockIdx.y * 128 + m + r) * 1024 + n] = acc[mi][nj][r];
    }
  }
}

// combine 8 partials + bias + relu -> hi/lo bf16 (or fp32)
__global__ __launch_bounds__(512)
void mlp_comb(const float* __restrict__ P, const float* __restrict__ bias,
              u16* __restrict__ Oh, u16* __restrict__ Ol,
              float* __restrict__ Of) {
#pragma unroll
  for (int e = 0; e < 8; ++e) {
    const int idx = blockIdx.x * 4096 + e * 512 + threadIdx.x;
    const int col = idx & 1023;
    float s = bias[col];
#pragma unroll
    for (int p = 0; p < 8; ++p) s += P[(size_t)p * 131072 + idx];
    s = fmaxf(s, 0.f);
    if (Oh) {
      const u16 h = f2bf(s);
      Oh[idx] = h;
      Ol[idx] = f2bf(s - bf2f(h));
    } else {
      Of[idx] = s;
    }
  }
}

__global__ __launch_bounds__(256)
void out_kernel(const float* __restrict__ T2, const float* __restrict__ Wout,
                const float* __restrict__ bout, float* __restrict__ out) {
  const int b = blockIdx.x;
  const int t = threadIdx.x;  // 256
  float a0 = 0.f, a1 = 0.f, a2 = 0.f;
  for (int k = t; k < 1024; k += 256) {
    const float x = T2[(size_t)b * 1024 + k];
    a0 = fmaf(x, Wout[k * 3 + 0], a0);
    a1 = fmaf(x, Wout[k * 3 + 1], a1);
    a2 = fmaf(x, Wout[k * 3 + 2], a2);
  }
  __shared__ float red[3][256];
  red[0][t] = a0; red[1][t] = a1; red[2][t] = a2;
  __syncthreads();
  for (int off = 128; off > 0; off >>= 1) {
    if (t < off) {
      red[0][t] += red[0][t + off];
      red[1][t] += red[1][t + off];
      red[2][t] += red[2][t + off];
    }
    __syncthreads();
  }
  if (t < 3) out[b * 3 + t] = red[t][0] + bout[t];
}

extern "C" void kernel_launch(void* const* d_in, const int* in_sizes, int n_in,
                              void* d_out, int out_size, void* d_ws, size_t ws_size,
                              hipStream_t stream) {
  (void)in_sizes; (void)n_in; (void)out_size; (void)ws_size;
  const float* embed = (const float*)d_in[0];
  const float* W1f   = (const float*)d_in[1];
  const float* W1r   = (const float*)d_in[2];
  const float* b1    = (const float*)d_in[3];
  const float* bn1g  = (const float*)d_in[4];
  const float* bn1b  = (const float*)d_in[5];
  const float* W2    = (const float*)d_in[6];
  const float* b2    = (const float*)d_in[7];
  const float* bn2g  = (const float*)d_in[8];
  const float* bn2b  = (const float*)d_in[9];
  const float* Wg    = (const float*)d_in[10];
  const float* bg    = (const float*)d_in[11];
  const float* Wf1   = (const float*)d_in[12];
  const float* bf1   = (const float*)d_in[13];
  const float* Wf2   = (const float*)d_in[14];
  const float* bf2   = (const float*)d_in[15];
  const float* Wout  = (const float*)d_in[16];
  const float* bout  = (const float*)d_in[17];
  const int* ids1    = (const int*)d_in[18];
  const int* ids2    = (const int*)d_in[19];

  char* wsp = (char*)d_ws;
  auto alloc = [&](size_t bytes) {
    char* p = wsp;
    wsp += (bytes + 255) & ~(size_t)255;
    return p;
  };
  u16* Hbf1  = (u16*)alloc((size_t)MROWS * DD * 2);
  u16* Hbf2  = (u16*)alloc((size_t)MROWS * DD * 2);
  u16* HT1   = (u16*)alloc((size_t)MROWS * DD * 2);
  u16* HT2   = (u16*)alloc((size_t)MROWS * DD * 2);
  u16* Xbf1  = (u16*)alloc((size_t)MROWS * 320 * 2);
  u16* Xbf2  = (u16*)alloc((size_t)MROWS * 320 * 2);
  u16* BETAb = (u16*)alloc((size_t)MROWS * DD * 2);
  u16* ALPHAb= (u16*)alloc((size_t)MROWS * DD * 2);
  float* SQP1= (float*)alloc((size_t)8 * MROWS * 4);
  float* SQP2= (float*)alloc((size_t)8 * MROWS * 4);
  u16* Wt1f  = (u16*)alloc((size_t)DD * 320 * 2);
  u16* Wt1r  = (u16*)alloc((size_t)9 * DD * DD * 2);
  u16* Wt2   = (u16*)alloc((size_t)10 * DD * 2 * DD * 2);
  u16* Wtg   = (u16*)alloc((size_t)10 * DD * DD * 2);
  u16* Wf1t  = (u16*)alloc((size_t)1024 * 1024 * 2);
  u16* Wf2t  = (u16*)alloc((size_t)1024 * 1024 * 2);
  u16* VPh   = (u16*)alloc((size_t)128 * 1024 * 2);
  u16* VPl   = (u16*)alloc((size_t)128 * 1024 * 2);
  u16* T1h   = (u16*)alloc((size_t)128 * 1024 * 2);
  u16* T1l   = (u16*)alloc((size_t)128 * 1024 * 2);
  float* T2f = (float*)alloc((size_t)128 * 1024 * 4);
  float* PART1 = (float*)alloc((size_t)8 * 128 * 1024 * 4);
  float* PART2 = (float*)alloc((size_t)8 * 128 * 1024 * 4);

  // weight conversion (transpose to n-major bf16)
  txw<<<dim3(5, 4, 1), 256, 0, stream>>>(W1f, Wt1f, EE, DD, 320);
  txw<<<dim3(4, 4, 9), 256, 0, stream>>>(W1r, Wt1r, DD, DD, DD);
  txw<<<dim3(8, 4, 10), 256, 0, stream>>>(W2, Wt2, 2 * DD, DD, 2 * DD);
  txw<<<dim3(4, 4, 10), 256, 0, stream>>>(Wg, Wtg, DD, DD, DD);
  txw<<<dim3(16, 16, 1), 256, 0, stream>>>(Wf1, Wf1t, 1024, 1024, 1024);
  txw<<<dim3(16, 16, 1), 256, 0, stream>>>(Wf2, Wf2t, 1024, 1024, 1024);
  gather_embed<<<dim3(MROWS / 4, 2), 256, 0, stream>>>(embed, ids1, ids2, Xbf1, Xbf2);

  for (int i = 0; i < NLAYERS; ++i) {
    const u16* Wt1 = (i == 0) ? Wt1f : (Wt1r + (size_t)(i - 1) * DD * DD);
    const int K1 = (i == 0) ? 320 : DD;
    const int lda = (i == 0) ? 320 : DD;
    lbr_nl<<<dim3(64, 4, 2), 256, 0, stream>>>(
        Xbf1, Xbf2, lda, K1, Wt1, b1 + i * DD, bn1g + i * DD, bn1b + i * DD,
        Hbf1, Hbf2, HT1, HT2, SQP1, SQP2);
    attf<<<dim3(NB, 2, 2), 256, 0, stream>>>(Hbf1, Hbf2, SQP1, SQP2, HT1, HT2,
                                             BETAb, ALPHAb);
    vg_nl<<<dim3(64, 4, 2), 256, 0, stream>>>(
        Hbf1, Hbf2, BETAb, ALPHAb, Wt2 + (size_t)i * DD * 2 * DD,
        Wtg + (size_t)i * DD * DD, b2 + i * DD, bn2g + i * DD, bn2b + i * DD,
        bg + i * DD, Xbf1, Xbf2);
  }
  pool_kernel<<<NB, DD, 0, stream>>>(Xbf1, Xbf2, VPh, VPl);
  mlp_sk<<<dim3(8, 8), 256, 0, stream>>>(VPh, VPl, Wf1t, PART1);
  mlp_comb<<<32, 512, 0, stream>>>(PART1, bf1, T1h, T1l, nullptr);
  mlp_sk<<<dim3(8, 8), 256, 0, stream>>>(T1h, T1l, Wf2t, PART2);
  mlp_comb<<<32, 512, 0, stream>>>(PART2, bf2, nullptr, nullptr, T2f);
  out_kernel<<<NB, 256, 0, stream>>>(T2f, Wout, bout, (float*)d_out);
}